// Round 7
// baseline (994.715 us; speedup 1.0000x reference)
//
#include <hip/hip_runtime.h>
#include <math.h>

// Depth collapses to d=0 (x[:, :, 0:1] slicing): conv1d -> w[3]*xi+b,
// scan at d=0 -> hs[0]=BX[0] (A_log unused), y = xi*(delta*sum(B*C)+D).
#define NB   2
#define CM   96      // D_MODEL
#define CI   192     // D_INNER
#define CO   384     // 2*D_INNER
#define HP   24
#define WP   24
#define PX   576
#define DTR  6
#define NDBC 38
#define CSPLIT 8
#define CCH  12      // input channels per conv chunk (96/CSPLIT)

#define NW_IN (2*CO*CM*9)      // 663552 in_proj elements
#define WQB_L (CM*CO*8)        // packed bf16 taps 0..7 per layer (ushorts)
#define WRB_L (CM*CO)          // tap 8 per layer (ushorts)
#define WPT_L (CI*CM)          // transposed out_proj per layer (floats)

__device__ __forceinline__ float siluf(float x){ return x / (1.f + expf(-x)); }
__device__ __forceinline__ float softplusf(float x){ return x > 20.f ? x : log1pf(expf(x)); }
__device__ __forceinline__ unsigned short f2bf(float f){
    unsigned u = __float_as_uint(f);
    return (unsigned short)((u + 0x7fffu + ((u >> 16) & 1u)) >> 16);
}
__device__ __forceinline__ float bflo(unsigned u){ return __uint_as_float(u << 16); }
__device__ __forceinline__ float bfhi(unsigned u){ return __uint_as_float(u & 0xffff0000u); }

// ---- prep: pack in_proj weights to bf16 [c][o][k0..7] + [c][o] tap8;
//            transpose out_proj -> wpT[l][c][m]
__global__ void prep_k(const float* __restrict__ ipw, const float* __restrict__ opw,
                       unsigned short* __restrict__ wQb, unsigned short* __restrict__ wRb,
                       float* __restrict__ wpT){
    int idx = blockIdx.x*256 + threadIdx.x;
    if (idx < NW_IN){
        int l = idx / (CO*CM*9);
        int r = idx % (CO*CM*9);
        int o = r / (CM*9);
        int r2 = r % (CM*9);
        int c = r2 / 9;
        int k = r2 % 9;
        unsigned short v = f2bf(ipw[idx]);
        if (k < 8) wQb[(long)l*WQB_L + ((c*CO + o)<<3) + k] = v;
        else       wRb[(long)l*WRB_L + c*CO + o] = v;
    } else {
        int j = idx - NW_IN;
        if (j < 2*CI*CM){
            int l = j / (CI*CM);
            int r = j % (CI*CM);
            int c = r / CM;
            int m = r % CM;
            wpT[l*WPT_L + c*CM + m] = opw[(l*CM + m)*CI + c];
        }
    }
}

// ---- layer: fused rmsnorm+conv (R4 core), then last-arriver ticket does
//             ssm + out_proj + residual for its 24-px row inline.
// grid (NB*HP, 6 og, CSPLIT cs), block 256. acc layout [cs][n][px][o].
__global__ __launch_bounds__(256, 4) void layer_k(
    const float* __restrict__ x, long nStr, long cStr,
    const float* __restrict__ nw,
    const unsigned short* __restrict__ wQb, const unsigned short* __restrict__ wRb,
    const float* __restrict__ c1w, const float* __restrict__ c1b,
    const float* __restrict__ xpw, const float* __restrict__ dtw,
    const float* __restrict__ dtb, const float* __restrict__ Dp,
    const float* __restrict__ wpT,
    int* __restrict__ cnt, float* __restrict__ acc, float* __restrict__ dst)
{
    __shared__ float hs[CCH][3][28];   // rows 16B-aligned
    __shared__ float scl[CCH][3];
    __shared__ float gl[4][CI];
    __shared__ int iswin;

    int bx = blockIdx.x;               // 0..47 : (n, row)
    int og = blockIdx.y;
    int cs = blockIdx.z;
    int n  = bx / HP, hh = bx % HP;
    int tid = threadIdx.x;
    int c0 = cs*CCH;

    // --- rmsnorm scales for the 3 input rows of this chunk
    if (tid < CCH*3){
        int c = tid/3, j = tid%3;
        int row = hh + j - 1;
        float s = 0.f;
        if (row >= 0 && row < HP){
            const float* xp = x + (long)n*nStr + (long)(c0+c)*cStr + row*WP;
            #pragma unroll
            for (int w = 0; w < WP; w++){ float v = xp[w]; s += v*v; }
            s = rsqrtf(s*(1.0f/WP) + 1e-5f) * nw[c0+c];
        }
        scl[c][j] = s;
    }
    __syncthreads();

    // --- stage normalized input tile
    for (int idx = tid; idx < CCH*3*28; idx += 256){
        int c = idx/84; int rem = idx%84; int j = rem/28; int wc = rem%28;
        int row = hh + j - 1;
        float v = 0.f;
        if (row >= 0 && row < HP && wc >= 1 && wc <= WP)
            v = x[(long)n*nStr + (long)(c0+c)*cStr + row*WP + (wc-1)] * scl[c][j];
        hs[c][j][wc] = v;
    }
    __syncthreads();

    // --- conv compute (one o per lane, 6-px strip per wave)
    {
        int ol = tid & 63;
        int o  = og*64 + ol;
        int x0 = (tid >> 6) * 6;       // even -> 8B-aligned float2 LDS loads
        float a0[6] = {0,0,0,0,0,0};
        const uint4* wq4 = (const uint4*)wQb;

        for (int c = 0; c < CCH; c++){
            int cg = c0 + c;
            uint4 wv = wq4[cg*CO + o];
            float w0 = bflo(wv.x), w1 = bfhi(wv.x);
            float w2 = bflo(wv.y), w3 = bfhi(wv.y);
            float w4 = bflo(wv.z), w5 = bfhi(wv.z);
            float w6 = bflo(wv.w), w7 = bfhi(wv.w);
            float w8 = bflo((unsigned)wRb[cg*CO + o]);
            float r0v[8], r1v[8], r2v[8];
            #pragma unroll
            for (int i = 0; i < 4; i++){
                float2 p0 = *(const float2*)(&hs[c][0][x0] + 2*i);
                float2 p1 = *(const float2*)(&hs[c][1][x0] + 2*i);
                float2 p2 = *(const float2*)(&hs[c][2][x0] + 2*i);
                r0v[2*i] = p0.x; r0v[2*i+1] = p0.y;
                r1v[2*i] = p1.x; r1v[2*i+1] = p1.y;
                r2v[2*i] = p2.x; r2v[2*i+1] = p2.y;
            }
            #pragma unroll
            for (int p = 0; p < 6; p++){
                a0[p] += w0*r0v[p] + w1*r0v[p+1] + w2*r0v[p+2]
                       + w3*r1v[p] + w4*r1v[p+1] + w5*r1v[p+2]
                       + w6*r2v[p] + w7*r2v[p+1] + w8*r2v[p+2];
            }
        }

        float* ap = acc + ((long)(cs*NB + n)*PX + hh*WP + x0)*CO + o;
        #pragma unroll
        for (int p = 0; p < 6; p++) ap[p*CO] = a0[p];
    }

    // --- last-arriver ticket: the 48th (og,cs) sibling for this row does ssm
    __threadfence();                           // release acc stores (device scope)
    if (tid == 0) iswin = (atomicAdd(&cnt[bx], 1) == 47) ? 1 : 0;
    __syncthreads();
    if (!iswin) return;
    __threadfence();                           // acquire others' acc stores

    int wave = tid >> 6, lane = tid & 63;
    for (int it = 0; it < 6; it++){
        int px = hh*WP + it*4 + wave;

        float xi[3], sz[3];
        #pragma unroll
        for (int t = 0; t < 3; t++){
            int c = lane + 64*t;
            float xr = 0.f, zr = 0.f;
            #pragma unroll
            for (int q = 0; q < CSPLIT; q++){
                const float* ap = acc + ((long)(q*NB + n)*PX + px)*CO;
                xr += ap[c]; zr += ap[CI + c];
            }
            xi[t] = siluf(xr*c1w[c*4 + 3] + c1b[c]);
            sz[t] = siluf(zr);
        }

        float dbc[NDBC];
        #pragma unroll
        for (int j = 0; j < NDBC; j++){
            float s = 0.f;
            #pragma unroll
            for (int t = 0; t < 3; t++) s += xi[t]*xpw[j*CI + lane + 64*t];
            dbc[j] = s;
        }
        #pragma unroll
        for (int step = 1; step < 64; step <<= 1){
            #pragma unroll
            for (int j = 0; j < NDBC; j++) dbc[j] += __shfl_xor(dbc[j], step, 64);
        }
        float BC = 0.f;
        #pragma unroll
        for (int s = 0; s < 16; s++) BC += dbc[6+s]*dbc[22+s];

        #pragma unroll
        for (int t = 0; t < 3; t++){
            int c = lane + 64*t;
            float dl = dtb[c];
            #pragma unroll
            for (int r = 0; r < DTR; r++) dl += dbc[r]*dtw[c*DTR + r];
            dl = softplusf(dl);
            gl[wave][c] = xi[t]*(dl*BC + Dp[c])*sz[t];
        }
        __syncthreads();

        for (int idx = tid; idx < 4*CM; idx += 256){
            int pl = idx / CM, m = idx % CM;
            int ppx = hh*WP + it*4 + pl;
            const float* g = gl[pl];
            float s0 = 0.f, s1 = 0.f, s2 = 0.f, s3 = 0.f;
            for (int c = 0; c < CI; c += 4){
                s0 += g[c+0]*wpT[(c+0)*CM + m];
                s1 += g[c+1]*wpT[(c+1)*CM + m];
                s2 += g[c+2]*wpT[(c+2)*CM + m];
                s3 += g[c+3]*wpT[(c+3)*CM + m];
            }
            float s = (s0+s1) + (s2+s3);
            s += x[(long)n*nStr + (long)m*cStr + ppx];
            dst[(n*CM + m)*PX + ppx] = s;
        }
        __syncthreads();   // gl reused next iteration
    }
}

extern "C" void kernel_launch(void* const* d_in, const int* in_sizes, int n_in,
                              void* d_out, int out_size, void* d_ws, size_t ws_size,
                              hipStream_t stream) {
    const float* x_in = (const float*)d_in[0];   // (2,96,8,24,24)
    const float* ipw  = (const float*)d_in[1];   // (2,384,96,1,3,3)
    const float* c1w  = (const float*)d_in[2];   // (2,192,1,4,1,1)
    const float* c1b  = (const float*)d_in[3];   // (2,192)
    const float* xpw  = (const float*)d_in[4];   // (2,38,192)
    const float* dtw  = (const float*)d_in[5];   // (2,192,6)
    const float* dtb  = (const float*)d_in[6];   // (2,192)
    // d_in[7] = A_log: unused at depth 0 (multiplies h[-1]=0)
    const float* Dp   = (const float*)d_in[8];   // (2,192)
    const float* opw  = (const float*)d_in[9];   // (2,96,192)
    const float* nw   = (const float*)d_in[10];  // (2,1,96,1,1,1)

    char* ws = (char*)d_ws;
    int* cnt = (int*)ws;                                    // 96 ints (384 B, 16B-mult)
    unsigned short* wQb = (unsigned short*)(ws + 384);      // 2*294912 ush
    unsigned short* wRb = wQb + 2*WQB_L;                    // 2*36864 ush
    float* wpT = (float*)(wRb + 2*WRB_L);                   // 2*18432 f
    float* acc = wpT + 2*WPT_L;                             // 8*2*576*384 f = 14.2 MB
    float* x1  = acc + (long)CSPLIT*NB*PX*CO;               // 110592 f

    hipMemsetAsync(cnt, 0, 2*NB*HP*sizeof(int), stream);    // zero tickets (ws is 0xAA)

    prep_k<<<(NW_IN + 2*CI*CM + 255)/256, 256, 0, stream>>>(ipw, opw, wQb, wRb, wpT);

    // ---- layer 0 (input: depth-0 slice of x, strides of (2,96,8,24,24))
    layer_k<<<dim3(NB*HP, 6, CSPLIT), 256, 0, stream>>>(
        x_in, 96L*8*PX, 8L*PX, nw, wQb, wRb,
        c1w, c1b, xpw, dtw, dtb, Dp, wpT,
        cnt, acc, x1);

    // ---- layer 1 (input x1 packed (2,96,24,24); writes final output)
    layer_k<<<dim3(NB*HP, 6, CSPLIT), 256, 0, stream>>>(
        x1, 96L*PX, (long)PX, nw + CM, wQb + WQB_L, wRb + WRB_L,
        c1w + CI*4, c1b + CI, xpw + NDBC*CI, dtw + CI*DTR, dtb + CI, Dp + CI, wpT + WPT_L,
        cnt + NB*HP, acc, (float*)d_out);
}

// Round 8
// 676.083 us; speedup vs baseline: 1.4713x; 1.4713x over previous
//
#include <hip/hip_runtime.h>
#include <hip/hip_cooperative_groups.h>
#include <math.h>

namespace cg = cooperative_groups;

// Depth collapses to d=0 (x[:, :, 0:1] slicing): conv1d -> w[3]*xi+b,
// scan at d=0 -> hs[0]=BX[0] (A_log unused), y = xi*(delta*sum(B*C)+D).
#define NB   2
#define CM   96      // D_MODEL
#define CI   192     // D_INNER
#define CO   384     // 2*D_INNER
#define HP   24
#define WP   24
#define PX   576
#define DTR  6
#define NDBC 38
#define CSPLIT 8
#define CCH  12      // input channels per conv chunk (96/CSPLIT)
#define GRIDN 768    // fused grid: 3 blocks/CU needed; launch_bounds gives >=4

#define NW_IN (2*CO*CM*9)      // 663552 in_proj elements
#define WQB_L (CM*CO*8)        // packed bf16 taps 0..7 per layer (ushorts)
#define WRB_L (CM*CO)          // tap 8 per layer (ushorts)
#define WPT_L (CI*CM)          // transposed out_proj per layer (floats)
#define PREP_TOT (NW_IN + 2*CI*CM)

__device__ __forceinline__ float siluf(float x){ return x / (1.f + expf(-x)); }
__device__ __forceinline__ float softplusf(float x){ return x > 20.f ? x : log1pf(expf(x)); }
__device__ __forceinline__ unsigned short f2bf(float f){
    unsigned u = __float_as_uint(f);
    return (unsigned short)((u + 0x7fffu + ((u >> 16) & 1u)) >> 16);
}
__device__ __forceinline__ float bflo(unsigned u){ return __uint_as_float(u << 16); }
__device__ __forceinline__ float bfhi(unsigned u){ return __uint_as_float(u & 0xffff0000u); }

struct ConvTile {
    float hs[CCH][3][28];   // rows 16B-aligned
    float scl[CCH][3];
};

// ---------- shared device helpers (used by both fused and fallback paths) ----------

__device__ __forceinline__ void prep_work(int idx,
    const float* __restrict__ ipw, const float* __restrict__ opw,
    unsigned short* __restrict__ wQb, unsigned short* __restrict__ wRb,
    float* __restrict__ wpT)
{
    if (idx < NW_IN){
        int l = idx / (CO*CM*9);
        int r = idx % (CO*CM*9);
        int o = r / (CM*9);
        int r2 = r % (CM*9);
        int c = r2 / 9;
        int k = r2 % 9;
        unsigned short v = f2bf(ipw[idx]);
        if (k < 8) wQb[(long)l*WQB_L + ((c*CO + o)<<3) + k] = v;
        else       wRb[(long)l*WRB_L + c*CO + o] = v;
    } else {
        int j = idx - NW_IN;
        int l = j / (CI*CM);
        int r = j % (CI*CM);
        int c = r / CM;
        int m = r % CM;
        wpT[l*WPT_L + c*CM + m] = opw[(l*CM + m)*CI + c];
    }
}

__device__ __forceinline__ void conv_stage(
    const float* __restrict__ x, long nStr, long cStr,
    const float* __restrict__ nwl, int n, int hh, int c0, int tid, ConvTile* t)
{
    if (tid < CCH*3){
        int c = tid/3, j = tid%3;
        int row = hh + j - 1;
        float s = 0.f;
        if (row >= 0 && row < HP){
            const float* xp = x + (long)n*nStr + (long)(c0+c)*cStr + row*WP;
            #pragma unroll
            for (int w = 0; w < WP; w++){ float v = xp[w]; s += v*v; }
            s = rsqrtf(s*(1.0f/WP) + 1e-5f) * nwl[c0+c];
        }
        t->scl[c][j] = s;
    }
    __syncthreads();
    for (int idx = tid; idx < CCH*3*28; idx += 256){
        int c = idx/84; int rem = idx%84; int j = rem/28; int wc = rem%28;
        int row = hh + j - 1;
        float v = 0.f;
        if (row >= 0 && row < HP && wc >= 1 && wc <= WP)
            v = x[(long)n*nStr + (long)(c0+c)*cStr + row*WP + (wc-1)] * t->scl[c][j];
        t->hs[c][j][wc] = v;
    }
    __syncthreads();
}

__device__ __forceinline__ void conv_og(
    const unsigned short* __restrict__ wQl, const unsigned short* __restrict__ wRl,
    const ConvTile* t, int c0, int og, int tid, float* __restrict__ accbase)
{
    int ol = tid & 63;
    int o  = og*64 + ol;
    int x0 = (tid >> 6) * 6;       // even -> 8B-aligned float2 LDS loads
    float a0[6] = {0,0,0,0,0,0};
    const uint4* wq4 = (const uint4*)wQl;

    for (int c = 0; c < CCH; c++){
        int cg = c0 + c;
        uint4 wv = wq4[cg*CO + o];
        float w0 = bflo(wv.x), w1 = bfhi(wv.x);
        float w2 = bflo(wv.y), w3 = bfhi(wv.y);
        float w4 = bflo(wv.z), w5 = bfhi(wv.z);
        float w6 = bflo(wv.w), w7 = bfhi(wv.w);
        float w8 = bflo((unsigned)wRl[cg*CO + o]);
        float r0v[8], r1v[8], r2v[8];
        #pragma unroll
        for (int i = 0; i < 4; i++){
            float2 p0 = *(const float2*)(&t->hs[c][0][x0] + 2*i);
            float2 p1 = *(const float2*)(&t->hs[c][1][x0] + 2*i);
            float2 p2 = *(const float2*)(&t->hs[c][2][x0] + 2*i);
            r0v[2*i] = p0.x; r0v[2*i+1] = p0.y;
            r1v[2*i] = p1.x; r1v[2*i+1] = p1.y;
            r2v[2*i] = p2.x; r2v[2*i+1] = p2.y;
        }
        #pragma unroll
        for (int p = 0; p < 6; p++){
            a0[p] += w0*r0v[p] + w1*r0v[p+1] + w2*r0v[p+2]
                   + w3*r1v[p] + w4*r1v[p+1] + w5*r1v[p+2]
                   + w6*r2v[p] + w7*r2v[p+1] + w8*r2v[p+2];
        }
    }
    float* ap = accbase + (long)x0*CO + o;
    #pragma unroll
    for (int p = 0; p < 6; p++) ap[p*CO] = a0[p];
}

__device__ __forceinline__ void ssm_block(int bb, int tid,
    const float* __restrict__ acc,
    const float* __restrict__ c1wl, const float* __restrict__ c1bl,
    const float* __restrict__ xpwl, const float* __restrict__ dtwl,
    const float* __restrict__ dtbl, const float* __restrict__ Dpl,
    const float* __restrict__ wpTl,
    const float* __restrict__ xsrc, long nStr, long cStr,
    float* __restrict__ dst, float (*gl)[CI])
{
    int wave = tid >> 6, lane = tid & 63;
    int p0 = bb*4;
    int p  = p0 + wave;
    int n  = p / PX, px = p % PX;

    float xi[3], sz[3];
    #pragma unroll
    for (int t = 0; t < 3; t++){
        int c = lane + 64*t;
        float xr = 0.f, zr = 0.f;
        #pragma unroll
        for (int q = 0; q < CSPLIT; q++){
            const float* ap = acc + ((long)(q*NB + n)*PX + px)*CO;
            xr += ap[c]; zr += ap[CI + c];
        }
        xi[t] = siluf(xr*c1wl[c*4 + 3] + c1bl[c]);
        sz[t] = siluf(zr);
    }

    float dbc[NDBC];
    #pragma unroll
    for (int j = 0; j < NDBC; j++){
        float s = 0.f;
        #pragma unroll
        for (int t = 0; t < 3; t++) s += xi[t]*xpwl[j*CI + lane + 64*t];
        dbc[j] = s;
    }
    #pragma unroll
    for (int step = 1; step < 64; step <<= 1){
        #pragma unroll
        for (int j = 0; j < NDBC; j++) dbc[j] += __shfl_xor(dbc[j], step, 64);
    }
    float BC = 0.f;
    #pragma unroll
    for (int s = 0; s < 16; s++) BC += dbc[6+s]*dbc[22+s];

    #pragma unroll
    for (int t = 0; t < 3; t++){
        int c = lane + 64*t;
        float dl = dtbl[c];
        #pragma unroll
        for (int r = 0; r < DTR; r++) dl += dbc[r]*dtwl[c*DTR + r];
        dl = softplusf(dl);
        gl[wave][c] = xi[t]*(dl*BC + Dpl[c])*sz[t];
    }
    __syncthreads();

    for (int idx = tid; idx < 4*CM; idx += 256){
        int pl = idx / CM, m = idx % CM;
        int pp = p0 + pl;
        int nn = pp / PX, ppx = pp % PX;
        const float* g = gl[pl];
        float s0 = 0.f, s1 = 0.f, s2 = 0.f, s3 = 0.f;
        for (int c = 0; c < CI; c += 4){
            s0 += g[c+0]*wpTl[(c+0)*CM + m];
            s1 += g[c+1]*wpTl[(c+1)*CM + m];
            s2 += g[c+2]*wpTl[(c+2)*CM + m];
            s3 += g[c+3]*wpTl[(c+3)*CM + m];
        }
        float s = (s0+s1) + (s2+s3);
        s += xsrc[(long)nn*nStr + (long)m*cStr + ppx];
        dst[(nn*CM + m)*PX + ppx] = s;
    }
    __syncthreads();   // gl reused by caller's next use
}

// ---------- fused cooperative kernel (primary path) ----------

__global__ __launch_bounds__(256, 4) void fused_k(
    const float* __restrict__ x_in, const float* __restrict__ ipw,
    const float* __restrict__ c1w,  const float* __restrict__ c1b,
    const float* __restrict__ xpw,  const float* __restrict__ dtw,
    const float* __restrict__ dtb,  const float* __restrict__ Dp,
    const float* __restrict__ opw,  const float* __restrict__ nw,
    float* __restrict__ out, char* __restrict__ wsb)
{
    cg::grid_group grid = cg::this_grid();
    unsigned short* wQb = (unsigned short*)wsb;
    unsigned short* wRb = wQb + 2*WQB_L;
    float* wpT = (float*)(wRb + 2*WRB_L);
    float* acc = wpT + 2*WPT_L;
    float* x1  = acc + (long)CSPLIT*NB*PX*CO;

    __shared__ ConvTile tile;
    __shared__ float gl[4][CI];

    int tid = threadIdx.x;
    int b   = blockIdx.x;

    for (int idx = b*256 + tid; idx < PREP_TOT; idx += GRIDN*256)
        prep_work(idx, ipw, opw, wQb, wRb, wpT);
    grid.sync();

    for (int l = 0; l < 2; l++){
        const float* xsrc = l ? x1 : x_in;
        long nStr = l ? 96L*PX : 96L*8*PX;
        long cStr = l ? (long)PX : 8L*PX;
        float* dst = l ? out : x1;
        const unsigned short* wQl = wQb + (long)l*WQB_L;
        const unsigned short* wRl = wRb + (long)l*WRB_L;

        // conv: b -> (rc = b/2 in 0..383 -> bx,cs ; oh = b&1), 3 og passes per block
        int rc = b >> 1;
        int bx = rc % 48, cs = rc / 48;
        int n  = bx / HP, hh = bx % HP;
        int c0 = cs*CCH, oh = b & 1;
        conv_stage(xsrc, nStr, cStr, nw + l*CM, n, hh, c0, tid, &tile);
        float* accbase = acc + ((long)(cs*NB + n)*PX + hh*WP)*CO;
        #pragma unroll
        for (int j = 0; j < 3; j++)
            conv_og(wQl, wRl, &tile, c0, oh*3 + j, tid, accbase);
        grid.sync();

        if (b < NB*PX/4)
            ssm_block(b, tid, acc,
                      c1w + l*CI*4, c1b + l*CI, xpw + l*NDBC*CI, dtw + l*CI*DTR,
                      dtb + l*CI, Dp + l*CI, wpT + l*WPT_L,
                      xsrc, nStr, cStr, dst, gl);
        grid.sync();
    }
}

// ---------- fallback kernels (exact R4 structure) ----------

__global__ void prep_k(const float* __restrict__ ipw, const float* __restrict__ opw,
                       unsigned short* __restrict__ wQb, unsigned short* __restrict__ wRb,
                       float* __restrict__ wpT){
    int idx = blockIdx.x*256 + threadIdx.x;
    if (idx < PREP_TOT) prep_work(idx, ipw, opw, wQb, wRb, wpT);
}

__global__ __launch_bounds__(256, 4) void conv_k(
    const float* __restrict__ x, long nStr, long cStr,
    const float* __restrict__ nwl,
    const unsigned short* __restrict__ wQl, const unsigned short* __restrict__ wRl,
    float* __restrict__ acc)
{
    __shared__ ConvTile tile;
    int bx = blockIdx.x, og = blockIdx.y, cs = blockIdx.z;
    int n = bx / HP, hh = bx % HP;
    int tid = threadIdx.x;
    int c0 = cs*CCH;
    conv_stage(x, nStr, cStr, nwl, n, hh, c0, tid, &tile);
    float* accbase = acc + ((long)(cs*NB + n)*PX + hh*WP)*CO;
    conv_og(wQl, wRl, &tile, c0, og, tid, accbase);
}

__global__ __launch_bounds__(256, 4) void ssmproj_k(
    const float* __restrict__ acc,
    const float* __restrict__ c1wl, const float* __restrict__ c1bl,
    const float* __restrict__ xpwl, const float* __restrict__ dtwl,
    const float* __restrict__ dtbl, const float* __restrict__ Dpl,
    const float* __restrict__ wpTl,
    const float* __restrict__ xres, long nStrR, long cStrR,
    float* __restrict__ dst)
{
    __shared__ float gl[4][CI];
    ssm_block(blockIdx.x, threadIdx.x, acc, c1wl, c1bl, xpwl, dtwl, dtbl, Dpl, wpTl,
              xres, nStrR, cStrR, dst, gl);
}

extern "C" void kernel_launch(void* const* d_in, const int* in_sizes, int n_in,
                              void* d_out, int out_size, void* d_ws, size_t ws_size,
                              hipStream_t stream) {
    const float* x_in = (const float*)d_in[0];   // (2,96,8,24,24)
    const float* ipw  = (const float*)d_in[1];   // (2,384,96,1,3,3)
    const float* c1w  = (const float*)d_in[2];   // (2,192,1,4,1,1)
    const float* c1b  = (const float*)d_in[3];   // (2,192)
    const float* xpw  = (const float*)d_in[4];   // (2,38,192)
    const float* dtw  = (const float*)d_in[5];   // (2,192,6)
    const float* dtb  = (const float*)d_in[6];   // (2,192)
    // d_in[7] = A_log: unused at depth 0 (multiplies h[-1]=0)
    const float* Dp   = (const float*)d_in[8];   // (2,192)
    const float* opw  = (const float*)d_in[9];   // (2,96,192)
    const float* nw   = (const float*)d_in[10];  // (2,1,96,1,1,1)

    char* wsb = (char*)d_ws;
    unsigned short* wQb = (unsigned short*)wsb;
    unsigned short* wRb = wQb + 2*WQB_L;
    float* wpT = (float*)(wRb + 2*WRB_L);
    float* acc = wpT + 2*WPT_L;
    float* x1  = acc + (long)CSPLIT*NB*PX*CO;
    float* outp = (float*)d_out;

    void* args[] = {
        (void*)&x_in, (void*)&ipw, (void*)&c1w, (void*)&c1b, (void*)&xpw,
        (void*)&dtw, (void*)&dtb, (void*)&Dp, (void*)&opw, (void*)&nw,
        (void*)&outp, (void*)&wsb
    };
    hipError_t err = hipLaunchCooperativeKernel((void*)fused_k, dim3(GRIDN), dim3(256),
                                                args, 0, stream);
    if (err != hipSuccess){
        (void)hipGetLastError();   // clear sticky error so harness checks stay clean

        prep_k<<<(PREP_TOT + 255)/256, 256, 0, stream>>>(ipw, opw, wQb, wRb, wpT);

        // layer 0 (input: depth-0 slice of x, strides of (2,96,8,24,24))
        conv_k<<<dim3(NB*HP, 6, CSPLIT), 256, 0, stream>>>(
            x_in, 96L*8*PX, 8L*PX, nw, wQb, wRb, acc);
        ssmproj_k<<<NB*PX/4, 256, 0, stream>>>(
            acc, c1w, c1b, xpw, dtw, dtb, Dp, wpT,
            x_in, 96L*8*PX, 8L*PX, x1);

        // layer 1 (input x1 packed (2,96,24,24); writes final output)
        conv_k<<<dim3(NB*HP, 6, CSPLIT), 256, 0, stream>>>(
            x1, 96L*PX, (long)PX, nw + CM, wQb + WQB_L, wRb + WRB_L, acc);
        ssmproj_k<<<NB*PX/4, 256, 0, stream>>>(
            acc, c1w + CI*4, c1b + CI, xpw + NDBC*CI, dtw + CI*DTR, dtb + CI, Dp + CI,
            wpT + WPT_L, x1, 96L*PX, (long)PX, outp);
    }
}

// Round 9
// 197.378 us; speedup vs baseline: 5.0396x; 3.4253x over previous
//
#include <hip/hip_runtime.h>
#include <math.h>

// Depth collapses to d=0 (x[:, :, 0:1] slicing): conv1d -> w[3]*xi+b,
// scan at d=0 -> hs[0]=BX[0] (A_log unused), y = xi*(delta*sum(B*C)+D).
// Lessons: grid.sync ~100us/ea on MI355X (R8), mid-kernel device fences poison
// the dispatch (R7), per-block LDS weight staging adds serial latency (R5).
// => 4 plain dispatches, kernel boundary as the only sync, per-lane VMEM weights.
#define NB   2
#define CM   96      // D_MODEL
#define CI   192     // D_INNER
#define CO   384     // 2*D_INNER
#define HP   24
#define WP   24
#define PX   576
#define DTR  6
#define NDBC 38
#define CSPLIT 8
#define CCH  12      // input channels per conv chunk (96/CSPLIT)

__device__ __forceinline__ float siluf(float x){ return x / (1.f + expf(-x)); }
__device__ __forceinline__ float softplusf(float x){ return x > 20.f ? x : log1pf(expf(x)); }

// ---- conv: fused rmsnorm + 3x3 conv (pad 1), raw fp32 weights read per-lane.
// grid (NB*HP, 6 og, CSPLIT cs), block 256 (4 waves x 6-px strips).
// acc layout: [cs][n][px][o]
__device__ __forceinline__ void conv_ch(
    const float (*hsrow)[3][28], int c, int x0,
    float w0, float w1, float w2, float w3, float w4,
    float w5, float w6, float w7, float w8, float* a0)
{
    float r0v[8], r1v[8], r2v[8];
    #pragma unroll
    for (int i = 0; i < 4; i++){
        float2 p0 = *(const float2*)(&hsrow[c][0][x0] + 2*i);
        float2 p1 = *(const float2*)(&hsrow[c][1][x0] + 2*i);
        float2 p2 = *(const float2*)(&hsrow[c][2][x0] + 2*i);
        r0v[2*i] = p0.x; r0v[2*i+1] = p0.y;
        r1v[2*i] = p1.x; r1v[2*i+1] = p1.y;
        r2v[2*i] = p2.x; r2v[2*i+1] = p2.y;
    }
    #pragma unroll
    for (int p = 0; p < 6; p++){
        a0[p] += w0*r0v[p] + w1*r0v[p+1] + w2*r0v[p+2]
               + w3*r1v[p] + w4*r1v[p+1] + w5*r1v[p+2]
               + w6*r2v[p] + w7*r2v[p+1] + w8*r2v[p+2];
    }
}

__global__ __launch_bounds__(256, 4) void conv_k(
    const float* __restrict__ x, long nStr, long cStr,
    const float* __restrict__ nwl,
    const float* __restrict__ ipwl,    // layer base: [o=384][c=96][k=9]
    float* __restrict__ acc)
{
    __shared__ float hs[CCH][3][28];   // rows 16B-aligned
    __shared__ float scl[CCH][3];
    int bx = blockIdx.x, og = blockIdx.y, cs = blockIdx.z;
    int n = bx / HP, hh = bx % HP;
    int tid = threadIdx.x;
    int c0 = cs*CCH;

    if (tid < CCH*3){
        int c = tid/3, j = tid%3;
        int row = hh + j - 1;
        float s = 0.f;
        if (row >= 0 && row < HP){
            const float* xp = x + (long)n*nStr + (long)(c0+c)*cStr + row*WP;
            #pragma unroll
            for (int w = 0; w < WP; w++){ float v = xp[w]; s += v*v; }
            s = rsqrtf(s*(1.0f/WP) + 1e-5f) * nwl[c0+c];
        }
        scl[c][j] = s;
    }
    __syncthreads();

    for (int idx = tid; idx < CCH*3*28; idx += 256){
        int c = idx/84; int rem = idx%84; int j = rem/28; int wc = rem%28;
        int row = hh + j - 1;
        float v = 0.f;
        if (row >= 0 && row < HP && wc >= 1 && wc <= WP)
            v = x[(long)n*nStr + (long)(c0+c)*cStr + row*WP + (wc-1)] * scl[c][j];
        hs[c][j][wc] = v;
    }
    __syncthreads();

    int ol = tid & 63;
    int o  = og*64 + ol;
    int x0 = (tid >> 6) * 6;           // even -> 8B-aligned float2 LDS loads
    float a0[6] = {0,0,0,0,0,0};

    // lane's weights: 108 consecutive floats at 16B-aligned offset
    // (o*864 + c0*9 floats; o*3456B and cs*432B both 16B multiples)
    const float4* wp = (const float4*)(ipwl + (long)o*(CM*9) + c0*9);

    #pragma unroll
    for (int g = 0; g < 3; g++){       // 4 channels per group, 9 float4 each
        float4 A = wp[g*9+0], B = wp[g*9+1], C = wp[g*9+2];
        float4 D = wp[g*9+3], E = wp[g*9+4], F = wp[g*9+5];
        float4 G = wp[g*9+6], H = wp[g*9+7], I = wp[g*9+8];
        conv_ch(hs, g*4+0, x0, A.x,A.y,A.z,A.w, B.x,B.y,B.z,B.w, C.x, a0);
        conv_ch(hs, g*4+1, x0, C.y,C.z,C.w, D.x,D.y,D.z,D.w, E.x,E.y, a0);
        conv_ch(hs, g*4+2, x0, E.z,E.w, F.x,F.y,F.z,F.w, G.x,G.y,G.z, a0);
        conv_ch(hs, g*4+3, x0, G.w, H.x,H.y,H.z,H.w, I.x,I.y,I.z,I.w, a0);
    }

    float* ap = acc + ((long)(cs*NB + n)*PX + hh*WP + x0)*CO + o;
    #pragma unroll
    for (int p = 0; p < 6; p++) ap[p*CO] = a0[p];
}

// ---- ssmproj: sum partials -> conv1d tap + SiLU gates -> x_proj/dt/BC -> gate ->
//               out_proj + residual. block 256 = 4 waves = 4 pixels; grid NB*PX/4.
__global__ __launch_bounds__(256, 4) void ssmproj_k(
    const float* __restrict__ acc,
    const float* __restrict__ c1wl, const float* __restrict__ c1bl,
    const float* __restrict__ xpwl, const float* __restrict__ dtwl,
    const float* __restrict__ dtbl, const float* __restrict__ Dpl,
    const float* __restrict__ opwl,   // layer base: [m=96][c=192]
    const float* __restrict__ xres, long nStrR, long cStrR,
    float* __restrict__ dst)
{
    __shared__ float gl[4][CI];
    int wave = threadIdx.x >> 6, lane = threadIdx.x & 63;
    int p0 = blockIdx.x*4;
    int p  = p0 + wave;
    int n  = p / PX, px = p % PX;

    float xi[3], sz[3];
    #pragma unroll
    for (int t = 0; t < 3; t++){
        int c = lane + 64*t;
        float xr = 0.f, zr = 0.f;
        #pragma unroll
        for (int q = 0; q < CSPLIT; q++){
            const float* ap = acc + ((long)(q*NB + n)*PX + px)*CO;
            xr += ap[c]; zr += ap[CI + c];
        }
        xi[t] = siluf(xr*c1wl[c*4 + 3] + c1bl[c]);
        sz[t] = siluf(zr);
    }

    float dbc[NDBC];
    #pragma unroll
    for (int j = 0; j < NDBC; j++){
        float s = 0.f;
        #pragma unroll
        for (int t = 0; t < 3; t++) s += xi[t]*xpwl[j*CI + lane + 64*t];
        dbc[j] = s;
    }
    #pragma unroll
    for (int step = 1; step < 64; step <<= 1){
        #pragma unroll
        for (int j = 0; j < NDBC; j++) dbc[j] += __shfl_xor(dbc[j], step, 64);
    }
    float BC = 0.f;
    #pragma unroll
    for (int s = 0; s < 16; s++) BC += dbc[6+s]*dbc[22+s];

    #pragma unroll
    for (int t = 0; t < 3; t++){
        int c = lane + 64*t;
        float dl = dtbl[c];
        #pragma unroll
        for (int r = 0; r < DTR; r++) dl += dbc[r]*dtwl[c*DTR + r];
        dl = softplusf(dl);
        gl[wave][c] = xi[t]*(dl*BC + Dpl[c])*sz[t];
    }
    __syncthreads();

    for (int idx = threadIdx.x; idx < 4*CM; idx += 256){
        int pl = idx / CM, m = idx % CM;
        int pp = p0 + pl;
        int nn = pp / PX, ppx = pp % PX;
        const float* g  = gl[pl];
        const float* wr = opwl + m*CI;       // per-lane contiguous row, L2-hot
        float s0 = 0.f, s1 = 0.f, s2 = 0.f, s3 = 0.f;
        for (int c = 0; c < CI; c += 4){
            float4 gv = *(const float4*)&g[c];
            float4 wv = *(const float4*)&wr[c];
            s0 += gv.x*wv.x; s1 += gv.y*wv.y; s2 += gv.z*wv.z; s3 += gv.w*wv.w;
        }
        float s = (s0+s1) + (s2+s3);
        s += xres[(long)nn*nStrR + (long)m*cStrR + ppx];
        dst[(nn*CM + m)*PX + ppx] = s;
    }
}

extern "C" void kernel_launch(void* const* d_in, const int* in_sizes, int n_in,
                              void* d_out, int out_size, void* d_ws, size_t ws_size,
                              hipStream_t stream) {
    const float* x_in = (const float*)d_in[0];   // (2,96,8,24,24)
    const float* ipw  = (const float*)d_in[1];   // (2,384,96,1,3,3)
    const float* c1w  = (const float*)d_in[2];   // (2,192,1,4,1,1)
    const float* c1b  = (const float*)d_in[3];   // (2,192)
    const float* xpw  = (const float*)d_in[4];   // (2,38,192)
    const float* dtw  = (const float*)d_in[5];   // (2,192,6)
    const float* dtb  = (const float*)d_in[6];   // (2,192)
    // d_in[7] = A_log: unused at depth 0 (multiplies h[-1]=0)
    const float* Dp   = (const float*)d_in[8];   // (2,192)
    const float* opw  = (const float*)d_in[9];   // (2,96,192)
    const float* nw   = (const float*)d_in[10];  // (2,1,96,1,1,1)

    float* acc = (float*)d_ws;                   // 8*2*576*384 f = 14.2 MB
    float* x1  = acc + (long)CSPLIT*NB*PX*CO;    // 110592 f

    // ---- layer 0 (input: depth-0 slice of x, strides of (2,96,8,24,24))
    conv_k<<<dim3(NB*HP, 6, CSPLIT), 256, 0, stream>>>(
        x_in, 96L*8*PX, 8L*PX, nw, ipw, acc);
    ssmproj_k<<<NB*PX/4, 256, 0, stream>>>(
        acc, c1w, c1b, xpw, dtw, dtb, Dp, opw,
        x_in, 96L*8*PX, 8L*PX, x1);

    // ---- layer 1 (input x1 packed (2,96,24,24); writes final output)
    conv_k<<<dim3(NB*HP, 6, CSPLIT), 256, 0, stream>>>(
        x1, 96L*PX, (long)PX, nw + CM, ipw + (long)CO*CM*9, acc);
    ssmproj_k<<<NB*PX/4, 256, 0, stream>>>(
        acc, c1w + CI*4, c1b + CI, xpw + NDBC*CI, dtw + CI*DTR, dtb + CI, Dp + CI,
        opw + CM*CI,
        x1, 96L*PX, (long)PX, (float*)d_out);
}